// Round 18
// baseline (342.939 us; speedup 1.0000x reference)
//
#include <hip/hip_runtime.h>
#include <hip/hip_bf16.h>

// LSH attention (Reformer-style), B=16, S=4096, D=128, H=8, bucket=64.
// norm -> prep_rot -> zero-LDS MFMA hash (hp-split, 4-term bf16, u64 argmax,
// rare f64 fallback) -> counting sort -> strip MFMA attention (8 chunks/block,
// K dbuf + single V buf = 49KB LDS -> 3 blocks/CU, f16 MFMA, permuted dense
// nt-stores) -> combine.

#define B_ 16
#define S_ 4096
#define D_ 128
#define H_ 8
#define C_ 512          // H * n_buckets
#define L_ 8            // chunks per strip
#define SCALE_ 0.08838834764831845f   // D^-0.5

typedef __attribute__((ext_vector_type(8))) short bf16x8;
typedef __attribute__((ext_vector_type(8))) _Float16 f16x8;
typedef __attribute__((ext_vector_type(2))) _Float16 f16x2t;
typedef __attribute__((ext_vector_type(4))) float f32x4;
typedef __attribute__((ext_vector_type(4))) int int4v;

union BF8U { int4v i; bf16x8 b; };
union F16x8U { int4v i; f16x8 h; };

__device__ __forceinline__ unsigned hi_pack(float x0, float x1) {
    unsigned a, b;
    __builtin_memcpy(&b, &x0, 4);
    __builtin_memcpy(&a, &x1, 4);
    return __builtin_amdgcn_perm(a, b, 0x07060302u);   // [x0.b2,x0.b3,x1.b2,x1.b3]
}
__device__ __forceinline__ float truncbf(float x) {
    unsigned u; __builtin_memcpy(&u, &x, 4);
    u &= 0xFFFF0000u;
    float f; __builtin_memcpy(&f, &u, 4);
    return f;
}
__device__ __forceinline__ unsigned pack2f16(float x0, float x1) {
    f16x2t h = {(_Float16)x0, (_Float16)x1};
    unsigned u; __builtin_memcpy(&u, &h, 4);
    return u;
}
__device__ __forceinline__ unsigned enc_ks(unsigned u) {
    return (u & 0x80000000u) ? ~u : (u | 0x80000000u);
}
__device__ __forceinline__ float dec_ks(unsigned ks) {
    unsigned u = (ks & 0x80000000u) ? (ks ^ 0x80000000u) : ~ks;
    float f; __builtin_memcpy(&f, &u, 4);
    return f;
}

// ---------------------------------------------------------------- row 1/norm
__global__ __launch_bounds__(256) void norm_kernel(const float* __restrict__ qk,
                                                   float* __restrict__ rnrm) {
    int half = threadIdx.x >> 5;
    int lane32 = threadIdx.x & 31;
    size_t row = (size_t)blockIdx.x * 8 + half;
    float4 vv = ((const float4*)(qk + row * D_))[lane32];
    float ss = vv.x * vv.x + vv.y * vv.y + vv.z * vv.z + vv.w * vv.w;
    #pragma unroll
    for (int m = 1; m < 32; m <<= 1) ss += __shfl_xor(ss, m, 64);
    if (lane32 == 0) rnrm[row] = 1.0f / fmaxf(sqrtf(ss), 1e-12f);
}

// ---------------------------------------------------------------- prep rot
__global__ __launch_bounds__(256) void prep_rot_kernel(const float* __restrict__ rot,
                                                       short* __restrict__ rth,
                                                       short* __restrict__ rtl) {
    int x = blockIdx.x * 256 + threadIdx.x;   // 0..8191
    int hp = x >> 11;
    int ia = (x >> 5) & 63;
    int ft = x & 31;
    float v0 = rot[(size_t)(ft * 4 + 0) * 256 + hp * 64 + ia];
    float v1 = rot[(size_t)(ft * 4 + 1) * 256 + hp * 64 + ia];
    float v2 = rot[(size_t)(ft * 4 + 2) * 256 + hp * 64 + ia];
    float v3 = rot[(size_t)(ft * 4 + 3) * 256 + hp * 64 + ia];
    unsigned h0 = hi_pack(v0, v1), h1 = hi_pack(v2, v3);
    unsigned l0 = hi_pack(v0 - truncbf(v0), v1 - truncbf(v1));
    unsigned l1 = hi_pack(v2 - truncbf(v2), v3 - truncbf(v3));
    int off = ia * 128 + ((((ft >> 1) ^ (ia & 7)) << 3) | ((ft & 1) << 2));
    *(int2*)&rth[hp * 8192 + off] = make_int2((int)h0, (int)h1);
    *(int2*)&rtl[hp * 8192 + off] = make_int2((int)l0, (int)l1);
}

// ---------------------------------------------------------------- MFMA hashing
// One block per (b, tile, hp). 4-term bf16 split (exact to f32 rounding).
__global__ __launch_bounds__(256, 4) void hash_kernel(
        const float* __restrict__ qk, const float* __restrict__ rot,
        const short* __restrict__ rth, const short* __restrict__ rtl,
        int* __restrict__ buckets) {
    __shared__ unsigned char flags[2][64];

    const int bid = blockIdx.x;
    const int b = bid >> 8;
    const int tile = (bid >> 2) & 63;
    const int hp = bid & 3;
    const int tid = threadIdx.x;
    const int w = tid >> 6, l = tid & 63, g = l >> 4, m = l & 15;

    if (tid < 8) ((int4*)flags)[tid] = make_int4(0, 0, 0, 0);
    __syncthreads();

    const float* qrow = qk + ((size_t)b * S_ + (size_t)tile * 64 + w * 16 + m) * D_;
    bf16x8 qh[4], qlr[4];
    #pragma unroll
    for (int s = 0; s < 4; ++s) {
        float4 xa = *(const float4*)(qrow + s * 32 + g * 8);
        float4 xb = *(const float4*)(qrow + s * 32 + g * 8 + 4);
        BF8U hu, lu;
        hu.i[0] = (int)hi_pack(xa.x, xa.y); hu.i[1] = (int)hi_pack(xa.z, xa.w);
        hu.i[2] = (int)hi_pack(xb.x, xb.y); hu.i[3] = (int)hi_pack(xb.z, xb.w);
        lu.i[0] = (int)hi_pack(xa.x - truncbf(xa.x), xa.y - truncbf(xa.y));
        lu.i[1] = (int)hi_pack(xa.z - truncbf(xa.z), xa.w - truncbf(xa.w));
        lu.i[2] = (int)hi_pack(xb.x - truncbf(xb.x), xb.y - truncbf(xb.y));
        lu.i[3] = (int)hi_pack(xb.z - truncbf(xb.z), xb.w - truncbf(xb.w));
        qh[s] = hu.b; qlr[s] = lu.b;
    }

    f32x4 dots_n[4];
    #pragma unroll
    for (int nt = 0; nt < 4; ++nt) {
        f32x4 acc = (f32x4){0.f, 0.f, 0.f, 0.f};
        #pragma unroll
        for (int s = 0; s < 4; ++s) {
            int kr = hp * 8192 + (nt * 16 + m) * 128 + (((s * 4 + g) ^ (m & 7)) << 3);
            bf16x8 bh = *(const bf16x8*)&rth[kr];
            bf16x8 bl = *(const bf16x8*)&rtl[kr];
            acc = __builtin_amdgcn_mfma_f32_16x16x32_bf16(qh[s], bh, acc, 0, 0, 0);
            acc = __builtin_amdgcn_mfma_f32_16x16x32_bf16(qh[s], bl, acc, 0, 0, 0);
            acc = __builtin_amdgcn_mfma_f32_16x16x32_bf16(qlr[s], bh, acc, 0, 0, 0);
            acc = __builtin_amdgcn_mfma_f32_16x16x32_bf16(qlr[s], bl, acc, 0, 0, 0);
        }
        dots_n[nt] = acc;
    }

    #pragma unroll
    for (int hh = 0; hh < 2; ++hh) {
        int h = hp * 2 + hh;
        #pragma unroll
        for (int r = 0; r < 4; ++r) {
            unsigned long long kM = 0ull, kS = 0ull;
            #pragma unroll
            for (int nn = 0; nn < 2; ++nn) {
                float v = dots_n[hh * 2 + nn][r];
                unsigned u; __builtin_memcpy(&u, &v, 4);
                int i = nn * 16 + m;
                unsigned long long kp =
                    ((unsigned long long)enc_ks(u) << 6) | (unsigned)(63 - i);
                unsigned long long kn =
                    ((unsigned long long)enc_ks(u ^ 0x80000000u) << 6) |
                    (unsigned)(63 - (i + 32));
                if (kp > kM) { kS = kM; kM = kp; } else if (kp > kS) kS = kp;
                if (kn > kM) { kS = kM; kM = kn; } else if (kn > kS) kS = kn;
            }
            #pragma unroll
            for (int st = 1; st <= 8; st <<= 1) {
                unsigned long long oM = __shfl_xor(kM, st, 64);
                unsigned long long oS = __shfl_xor(kS, st, 64);
                unsigned long long lo = kM < oM ? kM : oM;
                kM = kM > oM ? kM : oM;
                unsigned long long hs = kS > oS ? kS : oS;
                kS = hs > lo ? hs : lo;
            }
            if (m == 0) {
                int tok = w * 16 + g * 4 + r;
                int i1 = 63 - (int)(kM & 63ull);
                float v1 = dec_ks((unsigned)(kM >> 6));
                float v2 = dec_ks((unsigned)(kS >> 6));
                if (v1 - v2 < 1e-3f) flags[hh][tok] = 1;
                buckets[(((size_t)(b * H_ + h)) << 12) + tile * 64 + tok] = i1;
            }
        }
    }
    __syncthreads();

    int tok = tid >> 2, part = tid & 3;
    const float* qtok = qk + ((size_t)b * S_ + (size_t)tile * 64 + tok) * D_;
    for (int hh = 0; hh < 2; ++hh) {
        if (!flags[hh][tok]) continue;
        int h = hp * 2 + hh;
        double pd[8] = {0, 0, 0, 0, 0, 0, 0, 0};
        #pragma unroll 2
        for (int f = 0; f < 128; ++f) {
            double q = (double)qtok[f];
            const float* rp = rot + (size_t)f * 256 + h * 32 + part * 8;
            float4 r0 = *(const float4*)rp;
            float4 r1 = *(const float4*)(rp + 4);
            pd[0] = fma(q, (double)r0.x, pd[0]);
            pd[1] = fma(q, (double)r0.y, pd[1]);
            pd[2] = fma(q, (double)r0.z, pd[2]);
            pd[3] = fma(q, (double)r0.w, pd[3]);
            pd[4] = fma(q, (double)r1.x, pd[4]);
            pd[5] = fma(q, (double)r1.y, pd[5]);
            pd[6] = fma(q, (double)r1.z, pd[6]);
            pd[7] = fma(q, (double)r1.w, pd[7]);
        }
        double bv = -1e300; int bi = 0;
        #pragma unroll
        for (int ii = 0; ii < 8; ++ii) {
            int i = part * 8 + ii;
            double v = pd[ii];
            if (v > bv || (v == bv && i < bi)) { bv = v; bi = i; }
            double nv = -v; int ni = i + 32;
            if (nv > bv || (nv == bv && ni < bi)) { bv = nv; bi = ni; }
        }
        #pragma unroll
        for (int mm = 1; mm <= 2; mm <<= 1) {
            double ov = __shfl_xor(bv, mm, 64);
            int oi = __shfl_xor(bi, mm, 64);
            if (ov > bv || (ov == bv && oi < bi)) { bv = ov; bi = oi; }
        }
        if (part == 0)
            buckets[(((size_t)(b * H_ + h)) << 12) + tile * 64 + tok] = bi;
    }
}

// ---------------------------------------------------------------- stable counting sort
__global__ __launch_bounds__(256) void sort_kernel(const int* __restrict__ buckets,
                                                   int* __restrict__ st,
                                                   int* __restrict__ inv,
                                                   const float* __restrict__ rnrm,
                                                   float* __restrict__ rnrm_s) {
    __shared__ unsigned short hist[256][64];
    __shared__ int base[64];
    __shared__ int totals[64];
    int tid = threadIdx.x;
    const int* bkrow = buckets + (size_t)blockIdx.x * S_;
    const float* rnb = rnrm + (size_t)(blockIdx.x >> 3) * S_;

    unsigned int* h32 = (unsigned int*)hist;
    #pragma unroll
    for (int u = 0; u < 32; ++u) h32[u * 256 + tid] = 0;
    __syncthreads();

    #pragma unroll
    for (int u = 0; u < 16; ++u) {
        int t = tid * 16 + u;
        int bk = bkrow[t];
        hist[tid][bk]++;
    }
    __syncthreads();

    if (tid < 64) {
        int bucket = tid;
        int run = 0;
        for (int ch = 0; ch < 256; ++ch) {
            int v = hist[ch][bucket];
            hist[ch][bucket] = (unsigned short)run;
            run += v;
        }
        totals[bucket] = run;
    }
    __syncthreads();
    if (tid == 0) {
        int acc = 0;
        for (int k = 0; k < 64; ++k) { base[k] = acc; acc += totals[k]; }
    }
    __syncthreads();

    int* strow = st + (size_t)blockIdx.x * S_;
    int* invrow = inv + (size_t)blockIdx.x * S_;
    float* rnsrow = rnrm_s + (size_t)blockIdx.x * S_;
    #pragma unroll
    for (int u = 0; u < 16; ++u) {
        int t = tid * 16 + u;
        int bk = bkrow[t];
        int off = hist[tid][bk];
        hist[tid][bk] = (unsigned short)(off + 1);
        int pos = base[bk] + off;
        strow[pos] = t;
        invrow[t] = pos;
        rnsrow[pos] = rnb[t] * SCALE_;
    }
}

// ---------------------------------------------------------------- in-reg 4x4 transpose
__device__ __forceinline__ void transpose4(const float4 v, int g, float (&w_)[4]) {
    bool b0 = (g & 1) != 0, b1 = (g & 2) != 0;
    float k0 = b1 ? v.z : v.x;
    float k1 = b1 ? v.w : v.y;
    float s0 = b1 ? v.x : v.z;
    float s1 = b1 ? v.y : v.w;
    float r0 = __shfl_xor(s0, 32, 64);
    float r1 = __shfl_xor(s1, 32, 64);
    float kq_ = b0 ? k1 : k0;
    float rq_ = b0 ? r1 : r0;
    float sk  = b0 ? k0 : k1;
    float sr  = b0 ? r0 : r1;
    float tk_ = __shfl_xor(sk, 16, 64);
    float tr_ = __shfl_xor(sr, 16, 64);
    float A0 = b0 ? tk_ : kq_;
    float A1 = b0 ? kq_ : tk_;
    float B0 = b0 ? tr_ : rq_;
    float B1 = b0 ? rq_ : tr_;
    w_[0] = b1 ? B0 : A0;
    w_[1] = b1 ? B1 : A1;
    w_[2] = b1 ? A0 : B0;
    w_[3] = b1 ? A1 : B1;
}

// ---------------------------------------------------------------- strip MFMA attention
// One block per (b, strip of L_ chunks). K double-buffered, V SINGLE buffer:
// per chunk: write K(c); B1; QK self+prev, PV-prev (V(c-1) resident); B2;
// write V(c); B3; issue K(c+1); PV-self; permuted dense store.
template<bool DENSE>
__global__ __launch_bounds__(256, 3) void attn_strip_kernel(
        const float* __restrict__ qk, const float* __restrict__ rnrm_s,
        const float* __restrict__ vglob, const int* __restrict__ st,
        float* __restrict__ outnum, float* __restrict__ den,
        _Float16* __restrict__ snum, float* __restrict__ sden) {
    __shared__ int   toks[2][64];
    __shared__ float rnss[2][64];
    __shared__ short kbuf[2][8192];   // f16 K, swizzled (16 KB each)
    __shared__ short vbuf[8192];      // f16 V^T, swizzled (16 KB)

    // XCD swizzle: 1024 blocks -> each XCD gets 128 contiguous logical blocks.
    const int p = blockIdx.x;
    const int lg = (p & 7) * 128 + (p >> 3);
    const int b = lg >> 6;
    const int strip = lg & 63;
    const int c0 = strip * L_;
    const int tid = threadIdx.x;
    const int w = tid >> 6, l = tid & 63, g = l >> 4, m = l & 15;
    const size_t bS = ((size_t)b << 12);
    const int* stb = st + ((size_t)b << 15);

    auto rns_base = [&](int c) -> size_t {
        return (((size_t)(b * H_ + (c >> 6))) << 12) + (size_t)(c & 63) * 64;
    };

    float4 kreg[8];
    float4 va[4], vb[4];

    auto issue_k = [&](const int* __restrict__ tk) {
        #pragma unroll
        for (int u = 0; u < 8; ++u) {
            int token = u * 8 + (tid >> 5);
            int cc = tid & 31;
            kreg[u] = *(const float4*)(qk + (bS + tk[token]) * D_ + cc * 4);
        }
    };
    auto write_k = [&](short* __restrict__ kb) {
        #pragma unroll
        for (int u = 0; u < 8; ++u) {
            int token = u * 8 + (tid >> 5);
            int cc = tid & 31;
            float4 vv = kreg[u];
            unsigned h0 = pack2f16(vv.x, vv.y), h1 = pack2f16(vv.z, vv.w);
            int kw = token * 128 + ((((cc >> 1) ^ (token & 7)) << 3) | ((cc & 1) << 2));
            *(int2*)&kb[kw] = make_int2((int)h0, (int)h1);
        }
    };
    auto issue_v = [&](const int* __restrict__ tk) {
        #pragma unroll
        for (int up = 0; up < 4; ++up) {
            int kq8 = w * 16 + (up & 1) * 8;
            int cc = (up >> 1) * 16 + m;
            va[up] = *(const float4*)(vglob + (bS + tk[kq8 + g]) * D_ + cc * 4);
            vb[up] = *(const float4*)(vglob + (bS + tk[kq8 + 4 + g]) * D_ + cc * 4);
        }
    };
    auto write_v = [&]() {
        #pragma unroll
        for (int up = 0; up < 4; ++up) {
            int kq8 = w * 16 + (up & 1) * 8;
            int cc = (up >> 1) * 16 + m;
            float wa[4], wb[4];
            transpose4(va[up], g, wa);
            transpose4(vb[up], g, wb);
            unsigned h0 = pack2f16(wa[0], wa[1]), h1 = pack2f16(wa[2], wa[3]);
            unsigned h2 = pack2f16(wb[0], wb[1]), h3 = pack2f16(wb[2], wb[3]);
            int d = cc * 4 + g;
            int ds = d ^ ((d >> 3) & 7);
            int kg = kq8 >> 3;
            int idx = (kg * 128 + ds) * 8;
            *(int4*)&vbuf[idx] = make_int4((int)h0, (int)h1, (int)h2, (int)h3);
        }
    };

    // ---- prologue: lists for c0-1 (slot 1) and c0 (slot 0); stage K,V of c0-1
    const int cprev = (c0 + 511) & 511;
    if (tid < 64) {
        toks[1][tid] = stb[cprev * 64 + tid];
        rnss[1][tid] = rnrm_s[rns_base(cprev) + tid];
        toks[0][tid] = stb[c0 * 64 + tid];
        rnss[0][tid] = rnrm_s[rns_base(c0) + tid];
    }
    __syncthreads();
    issue_k(toks[1]);
    issue_v(toks[1]);
    write_k(kbuf[1]);
    write_v();
    __syncthreads();
    issue_k(toks[0]);                   // gather K of first chunk

    #pragma unroll 1
    for (int j = 0; j < L_; ++j) {
        const int c = c0 + j;
        const int cur = j & 1, prv = cur ^ 1;
        short* kbc = kbuf[cur];
        short* kbp = kbuf[prv];

        // ---- write K(c) (gathered last iteration / prologue)
        write_k(kbc);
        __syncthreads();                // B1: kbc visible

        // ---- Q frags from kbc; issue V(c) gather; QK self+prev; PV-prev
        f16x8 qh[4];
        #pragma unroll
        for (int s4 = 0; s4 < 4; ++s4) {
            int qr = (w * 16 + m) * 128 + (((s4 * 4 + g) ^ (m & 7)) << 3);
            qh[s4] = *(const f16x8*)&kbc[qr];
        }
        const int qtok_m = toks[cur][w * 16 + m];
        issue_v(toks[cur]);

        f32x4 e4s[4], e4p[4];
        float densum = 0.f;
        auto qk_one = [&](const short* __restrict__ kb,
                          const float* __restrict__ rns,
                          const int* __restrict__ tkp, int mode,
                          f32x4 (&e4)[4]) {
            #pragma unroll
            for (int kt = 0; kt < 4; ++kt) {
                f32x4 acc = (f32x4){0.f, 0.f, 0.f, 0.f};
                #pragma unroll
                for (int s4 = 0; s4 < 4; ++s4) {
                    int kr = (kt * 16 + m) * 128 + (((s4 * 4 + g) ^ (m & 7)) << 3);
                    f16x8 ah = *(const f16x8*)&kb[kr];
                    acc = __builtin_amdgcn_mfma_f32_16x16x32_f16(ah, qh[s4], acc, 0, 0, 0);
                }
                f32x4 rn4 = *(const f32x4*)&rns[kt * 16 + g * 4];
                int4v kt4;
                if (mode == 1) kt4 = *(const int4v*)&tkp[kt * 16 + g * 4];
                f32x4 e;
                #pragma unroll
                for (int r = 0; r < 4; ++r) {
                    float ev = __expf(acc[r] * rn4[r]);
                    if (mode == 0) {
                        if (kt == w && (g * 4 + r) == m) ev = 0.0f;
                    } else {
                        if (kt4[r] == qtok_m) ev = 0.0f;
                    }
                    e[r] = ev;
                    densum += ev;
                }
                e4[kt] = e;
            }
        };
        qk_one(kbc, rnss[cur], toks[cur], 0, e4s);
        qk_one(kbp, rnss[prv], toks[prv], 1, e4p);

        f32x4 acc_o[8];
        #pragma unroll
        for (int dt = 0; dt < 8; ++dt) acc_o[dt] = (f32x4){0.f, 0.f, 0.f, 0.f};
        auto pv_one = [&](const f32x4 (&e4)[4]) {
            #pragma unroll
            for (int s = 0; s < 2; ++s) {
                float pav[8];
                #pragma unroll
                for (int c2 = 0; c2 < 2; ++c2) {
                    int srcLane = ((g & 1) * 2 + c2) * 16 + m;
                    #pragma unroll
                    for (int r = 0; r < 4; ++r) {
                        float v0 = __shfl(e4[2 * s][r], srcLane, 64);
                        float v1 = __shfl(e4[2 * s + 1][r], srcLane, 64);
                        pav[c2 * 4 + r] = (g >> 1) ? v1 : v0;
                    }
                }
                F16x8U pahu;
                #pragma unroll
                for (int j2 = 0; j2 < 4; ++j2)
                    pahu.i[j2] = (int)pack2f16(pav[2 * j2], pav[2 * j2 + 1]);
                f16x8 pah = pahu.h;
                #pragma unroll
                for (int dt = 0; dt < 8; ++dt) {
                    int d = dt * 16 + m;
                    int ds = d ^ ((d >> 3) & 7);
                    int base = ((s * 4 + g) * 128 + ds) * 8;
                    f16x8 vh = *(const f16x8*)&vbuf[base];
                    acc_o[dt] = __builtin_amdgcn_mfma_f32_16x16x32_f16(pah, vh, acc_o[dt], 0, 0, 0);
                }
            }
        };
        pv_one(e4p);                    // PV-prev: V(c-1) still in vbuf
        __syncthreads();                // B2: V(c-1)/K(prv)/list reads done

        // prefetch next chunk's list into the slot being freed (prv)
        if (j + 1 < L_ && tid < 64) {
            int cn = c + 1;
            toks[prv][tid] = stb[cn * 64 + tid];
            rnss[prv][tid] = rnrm_s[rns_base(cn) + tid];
        }
        write_v();                      // V(c) overwrites vbuf
        __syncthreads();                // B3: vbuf + prefetch visible

        if (j + 1 < L_) issue_k(toks[prv]);   // next K gather under PV-self

        pv_one(e4s);                    // PV-self: V(c)

        // ---- epilogue for chunk c
        densum += __shfl_xor(densum, 16, 64);
        densum += __shfl_xor(densum, 32, 64);

        if (DENSE) {
            const int hH = c >> 6;
            const size_t basepos = (((size_t)(b * H_ + hH)) << 12) + (size_t)(c & 63) * 64;
            // permuted row layout: position m*8+dt holds dim dt*16+m
            #pragma unroll
            for (int r = 0; r < 4; ++r) {
                int row = w * 16 + g * 4 + r;
                int4v pk;
                pk[0] = (int)pack2f16(acc_o[0][r], acc_o[1][r]);
                pk[1] = (int)pack2f16(acc_o[2][r], acc_o[3][r]);
                pk[2] = (int)pack2f16(acc_o[4][r], acc_o[5][r]);
                pk[3] = (int)pack2f16(acc_o[6][r], acc_o[7][r]);
                __builtin_nontemporal_store(
                    pk, (int4v*)(snum + (basepos + row) * D_ + m * 8));
            }
            if (g == 0) __builtin_nontemporal_store(densum, sden + basepos + w * 16 + m);
        } else {
            if (g == 0) atomicAdd(den + bS + qtok_m, densum);
            int4v q4tok = *(const int4v*)&toks[cur][w * 16 + g * 4];
            #pragma unroll
            for (int r = 0; r < 4; ++r) {
                float* obase = outnum + ((bS + q4tok[r]) * D_);
                #pragma unroll
                for (int dt = 0; dt < 8; ++dt)
                    atomicAdd(obase + dt * 16 + m, acc_o[dt][r]);
            }
        }
    }
}

// ---------------------------------------------------------------- combine
// snum rows are permuted: position p holds dim 16*(p&7) + (p>>3).
__global__ __launch_bounds__(256) void combine_kernel(
        const _Float16* __restrict__ snum, const float* __restrict__ sden,
        const int* __restrict__ inv, float* __restrict__ out) {
    int wv = threadIdx.x >> 6, l = threadIdx.x & 63;
    int t = blockIdx.x * 4 + wv;          // 0 .. B*S-1
    int b = t >> 12, s = t & 4095;
    float s0 = 0.f, s1 = 0.f, dsum = 0.f;
    #pragma unroll
    for (int h = 0; h < H_; ++h) {
        int bh = b * H_ + h;
        int pos = inv[((size_t)bh << 12) + s];
        size_t row = ((size_t)bh << 12) + pos;
        dsum += __builtin_nontemporal_load(sden + row);
        unsigned uv = __builtin_nontemporal_load(
            (const unsigned*)(snum + row * D_ + 2 * l));
        unsigned short us0 = (unsigned short)(uv & 0xFFFFu);
        unsigned short us1 = (unsigned short)(uv >> 16);
        _Float16 h0, h1;
        __builtin_memcpy(&h0, &us0, 2);
        __builtin_memcpy(&h1, &us1, 2);
        s0 += (float)h0;
        s1 += (float)h1;
    }
    float rd = 1.0f / dsum;
    int d0 = ((2 * l) & 7) * 16 + (l >> 2);   // dim of half 2l; half 2l+1 -> d0+16
    __builtin_nontemporal_store(s0 * rd, out + (size_t)t * D_ + d0);
    __builtin_nontemporal_store(s1 * rd, out + (size_t)t * D_ + d0 + 16);
}

// ---------------------------------------------------------------- divide (fallback)
__global__ __launch_bounds__(256) void div_kernel(float* __restrict__ out,
                                                  const float* __restrict__ den) {
    int i = blockIdx.x * 256 + threadIdx.x;
    float4 o = ((float4*)out)[i];
    float dn = den[i >> 5];
    ((float4*)out)[i] = make_float4(o.x / dn, o.y / dn, o.z / dn, o.w / dn);
}

// ---------------------------------------------------------------- launch
extern "C" void kernel_launch(void* const* d_in, const int* in_sizes, int n_in,
                              void* d_out, int out_size, void* d_ws, size_t ws_size,
                              hipStream_t stream) {
    const float* qk  = (const float*)d_in[0];
    const float* v   = (const float*)d_in[1];
    const float* rot = (const float*)d_in[2];
    float* out = (float*)d_out;

    char* ws = (char*)d_ws;
    float* rnrm    = (float*)ws;                        //   262,144 B
    int* buckets   = (int*)(ws + 262144);               // 2,097,152 B
    int* inv       = buckets;                           // aliased (RAW per index)
    int* st        = (int*)(ws + 2359296);              // 2,097,152 B
    float* rnrm_s  = (float*)(ws + 4456448);            // 2,097,152 B
    float* sden    = (float*)(ws + 6553600);            // 2,097,152 B
    short* rth     = (short*)(ws + 8650752);            //    65,536 B
    short* rtl     = (short*)(ws + 8716288);            //    65,536 B
    _Float16* snum = (_Float16*)(ws + 8781824);         // 134,217,728 B
    const size_t need = 8781824ull + 134217728ull;

    norm_kernel<<<B_ * S_ / 8, 256, 0, stream>>>(qk, rnrm);
    prep_rot_kernel<<<32, 256, 0, stream>>>(rot, rth, rtl);
    hash_kernel<<<B_ * (S_ / 64) * 4, 256, 0, stream>>>(qk, rot, rth, rtl, buckets);
    sort_kernel<<<B_ * H_, 256, 0, stream>>>(buckets, st, inv, rnrm, rnrm_s);

    if (ws_size >= need) {
        attn_strip_kernel<true><<<B_ * C_ / L_, 256, 0, stream>>>(
            qk, rnrm_s, v, st, nullptr, nullptr, snum, sden);
        combine_kernel<<<B_ * S_ / 4, 256, 0, stream>>>(snum, sden, inv, out);
    } else {
        float* den = sden;
        hipMemsetAsync(out, 0, (size_t)B_ * S_ * D_ * 4, stream);
        hipMemsetAsync(den, 0, (size_t)B_ * S_ * 4, stream);
        attn_strip_kernel<false><<<B_ * C_ / L_, 256, 0, stream>>>(
            qk, rnrm_s, v, st, out, den, nullptr, nullptr);
        div_kernel<<<B_ * S_ * D_ / 4 / 256, 256, 0, stream>>>(out, den);
    }
}

// Round 19
// 223.203 us; speedup vs baseline: 1.5364x; 1.5364x over previous
//
#include <hip/hip_runtime.h>
#include <hip/hip_bf16.h>

// LSH attention (Reformer-style), B=16, S=4096, D=128, H=8, bucket=64.
// norm -> prep_rot -> zero-LDS MFMA hash (hp-split, 4-term bf16, u64 argmax,
// rare f64 fallback) -> counting sort -> strip MFMA attention (8 chunks/block,
// K/V staged once, double-buffered, f16 MFMA, dense nt-stores) -> combine.

#define B_ 16
#define S_ 4096
#define D_ 128
#define H_ 8
#define C_ 512          // H * n_buckets
#define L_ 8            // chunks per strip
#define SCALE_ 0.08838834764831845f   // D^-0.5

typedef __attribute__((ext_vector_type(8))) short bf16x8;
typedef __attribute__((ext_vector_type(8))) _Float16 f16x8;
typedef __attribute__((ext_vector_type(2))) _Float16 f16x2t;
typedef __attribute__((ext_vector_type(4))) float f32x4;
typedef __attribute__((ext_vector_type(2))) float f32x2v;
typedef __attribute__((ext_vector_type(4))) int int4v;

union BF8U { int4v i; bf16x8 b; };
union F16x8U { int4v i; f16x8 h; };

__device__ __forceinline__ unsigned hi_pack(float x0, float x1) {
    unsigned a, b;
    __builtin_memcpy(&b, &x0, 4);
    __builtin_memcpy(&a, &x1, 4);
    return __builtin_amdgcn_perm(a, b, 0x07060302u);   // [x0.b2,x0.b3,x1.b2,x1.b3]
}
__device__ __forceinline__ float truncbf(float x) {
    unsigned u; __builtin_memcpy(&u, &x, 4);
    u &= 0xFFFF0000u;
    float f; __builtin_memcpy(&f, &u, 4);
    return f;
}
__device__ __forceinline__ unsigned pack2f16(float x0, float x1) {
    f16x2t h = {(_Float16)x0, (_Float16)x1};
    unsigned u; __builtin_memcpy(&u, &h, 4);
    return u;
}
__device__ __forceinline__ unsigned enc_ks(unsigned u) {
    return (u & 0x80000000u) ? ~u : (u | 0x80000000u);
}
__device__ __forceinline__ float dec_ks(unsigned ks) {
    unsigned u = (ks & 0x80000000u) ? (ks ^ 0x80000000u) : ~ks;
    float f; __builtin_memcpy(&f, &u, 4);
    return f;
}

// ---------------------------------------------------------------- row 1/norm
__global__ __launch_bounds__(256) void norm_kernel(const float* __restrict__ qk,
                                                   float* __restrict__ rnrm) {
    int half = threadIdx.x >> 5;
    int lane32 = threadIdx.x & 31;
    size_t row = (size_t)blockIdx.x * 8 + half;
    float4 vv = ((const float4*)(qk + row * D_))[lane32];
    float ss = vv.x * vv.x + vv.y * vv.y + vv.z * vv.z + vv.w * vv.w;
    #pragma unroll
    for (int m = 1; m < 32; m <<= 1) ss += __shfl_xor(ss, m, 64);
    if (lane32 == 0) rnrm[row] = 1.0f / fmaxf(sqrtf(ss), 1e-12f);
}

// ---------------------------------------------------------------- prep rot
__global__ __launch_bounds__(256) void prep_rot_kernel(const float* __restrict__ rot,
                                                       short* __restrict__ rth,
                                                       short* __restrict__ rtl) {
    int x = blockIdx.x * 256 + threadIdx.x;   // 0..8191
    int hp = x >> 11;
    int ia = (x >> 5) & 63;
    int ft = x & 31;
    float v0 = rot[(size_t)(ft * 4 + 0) * 256 + hp * 64 + ia];
    float v1 = rot[(size_t)(ft * 4 + 1) * 256 + hp * 64 + ia];
    float v2 = rot[(size_t)(ft * 4 + 2) * 256 + hp * 64 + ia];
    float v3 = rot[(size_t)(ft * 4 + 3) * 256 + hp * 64 + ia];
    unsigned h0 = hi_pack(v0, v1), h1 = hi_pack(v2, v3);
    unsigned l0 = hi_pack(v0 - truncbf(v0), v1 - truncbf(v1));
    unsigned l1 = hi_pack(v2 - truncbf(v2), v3 - truncbf(v3));
    int off = ia * 128 + ((((ft >> 1) ^ (ia & 7)) << 3) | ((ft & 1) << 2));
    *(int2*)&rth[hp * 8192 + off] = make_int2((int)h0, (int)h1);
    *(int2*)&rtl[hp * 8192 + off] = make_int2((int)l0, (int)l1);
}

// ---------------------------------------------------------------- MFMA hashing
// One block per (b, tile, hp). 4-term bf16 split (exact to f32 rounding).
__global__ __launch_bounds__(256, 4) void hash_kernel(
        const float* __restrict__ qk, const float* __restrict__ rot,
        const short* __restrict__ rth, const short* __restrict__ rtl,
        int* __restrict__ buckets) {
    __shared__ unsigned char flags[2][64];

    const int bid = blockIdx.x;
    const int b = bid >> 8;
    const int tile = (bid >> 2) & 63;
    const int hp = bid & 3;
    const int tid = threadIdx.x;
    const int w = tid >> 6, l = tid & 63, g = l >> 4, m = l & 15;

    if (tid < 8) ((int4*)flags)[tid] = make_int4(0, 0, 0, 0);
    __syncthreads();

    const float* qrow = qk + ((size_t)b * S_ + (size_t)tile * 64 + w * 16 + m) * D_;
    bf16x8 qh[4], qlr[4];
    #pragma unroll
    for (int s = 0; s < 4; ++s) {
        float4 xa = *(const float4*)(qrow + s * 32 + g * 8);
        float4 xb = *(const float4*)(qrow + s * 32 + g * 8 + 4);
        BF8U hu, lu;
        hu.i[0] = (int)hi_pack(xa.x, xa.y); hu.i[1] = (int)hi_pack(xa.z, xa.w);
        hu.i[2] = (int)hi_pack(xb.x, xb.y); hu.i[3] = (int)hi_pack(xb.z, xb.w);
        lu.i[0] = (int)hi_pack(xa.x - truncbf(xa.x), xa.y - truncbf(xa.y));
        lu.i[1] = (int)hi_pack(xa.z - truncbf(xa.z), xa.w - truncbf(xa.w));
        lu.i[2] = (int)hi_pack(xb.x - truncbf(xb.x), xb.y - truncbf(xb.y));
        lu.i[3] = (int)hi_pack(xb.z - truncbf(xb.z), xb.w - truncbf(xb.w));
        qh[s] = hu.b; qlr[s] = lu.b;
    }

    f32x4 dots_n[4];
    #pragma unroll
    for (int nt = 0; nt < 4; ++nt) {
        f32x4 acc = (f32x4){0.f, 0.f, 0.f, 0.f};
        #pragma unroll
        for (int s = 0; s < 4; ++s) {
            int kr = hp * 8192 + (nt * 16 + m) * 128 + (((s * 4 + g) ^ (m & 7)) << 3);
            bf16x8 bh = *(const bf16x8*)&rth[kr];
            bf16x8 bl = *(const bf16x8*)&rtl[kr];
            acc = __builtin_amdgcn_mfma_f32_16x16x32_bf16(qh[s], bh, acc, 0, 0, 0);
            acc = __builtin_amdgcn_mfma_f32_16x16x32_bf16(qh[s], bl, acc, 0, 0, 0);
            acc = __builtin_amdgcn_mfma_f32_16x16x32_bf16(qlr[s], bh, acc, 0, 0, 0);
            acc = __builtin_amdgcn_mfma_f32_16x16x32_bf16(qlr[s], bl, acc, 0, 0, 0);
        }
        dots_n[nt] = acc;
    }

    #pragma unroll
    for (int hh = 0; hh < 2; ++hh) {
        int h = hp * 2 + hh;
        #pragma unroll
        for (int r = 0; r < 4; ++r) {
            unsigned long long kM = 0ull, kS = 0ull;
            #pragma unroll
            for (int nn = 0; nn < 2; ++nn) {
                float v = dots_n[hh * 2 + nn][r];
                unsigned u; __builtin_memcpy(&u, &v, 4);
                int i = nn * 16 + m;
                unsigned long long kp =
                    ((unsigned long long)enc_ks(u) << 6) | (unsigned)(63 - i);
                unsigned long long kn =
                    ((unsigned long long)enc_ks(u ^ 0x80000000u) << 6) |
                    (unsigned)(63 - (i + 32));
                if (kp > kM) { kS = kM; kM = kp; } else if (kp > kS) kS = kp;
                if (kn > kM) { kS = kM; kM = kn; } else if (kn > kS) kS = kn;
            }
            #pragma unroll
            for (int st = 1; st <= 8; st <<= 1) {
                unsigned long long oM = __shfl_xor(kM, st, 64);
                unsigned long long oS = __shfl_xor(kS, st, 64);
                unsigned long long lo = kM < oM ? kM : oM;
                kM = kM > oM ? kM : oM;
                unsigned long long hs = kS > oS ? kS : oS;
                kS = hs > lo ? hs : lo;
            }
            if (m == 0) {
                int tok = w * 16 + g * 4 + r;
                int i1 = 63 - (int)(kM & 63ull);
                float v1 = dec_ks((unsigned)(kM >> 6));
                float v2 = dec_ks((unsigned)(kS >> 6));
                if (v1 - v2 < 1e-3f) flags[hh][tok] = 1;
                buckets[(((size_t)(b * H_ + h)) << 12) + tile * 64 + tok] = i1;
            }
        }
    }
    __syncthreads();

    int tok = tid >> 2, part = tid & 3;
    const float* qtok = qk + ((size_t)b * S_ + (size_t)tile * 64 + tok) * D_;
    for (int hh = 0; hh < 2; ++hh) {
        if (!flags[hh][tok]) continue;
        int h = hp * 2 + hh;
        double pd[8] = {0, 0, 0, 0, 0, 0, 0, 0};
        #pragma unroll 2
        for (int f = 0; f < 128; ++f) {
            double q = (double)qtok[f];
            const float* rp = rot + (size_t)f * 256 + h * 32 + part * 8;
            float4 r0 = *(const float4*)rp;
            float4 r1 = *(const float4*)(rp + 4);
            pd[0] = fma(q, (double)r0.x, pd[0]);
            pd[1] = fma(q, (double)r0.y, pd[1]);
            pd[2] = fma(q, (double)r0.z, pd[2]);
            pd[3] = fma(q, (double)r0.w, pd[3]);
            pd[4] = fma(q, (double)r1.x, pd[4]);
            pd[5] = fma(q, (double)r1.y, pd[5]);
            pd[6] = fma(q, (double)r1.z, pd[6]);
            pd[7] = fma(q, (double)r1.w, pd[7]);
        }
        double bv = -1e300; int bi = 0;
        #pragma unroll
        for (int ii = 0; ii < 8; ++ii) {
            int i = part * 8 + ii;
            double v = pd[ii];
            if (v > bv || (v == bv && i < bi)) { bv = v; bi = i; }
            double nv = -v; int ni = i + 32;
            if (nv > bv || (nv == bv && ni < bi)) { bv = nv; bi = ni; }
        }
        #pragma unroll
        for (int mm = 1; mm <= 2; mm <<= 1) {
            double ov = __shfl_xor(bv, mm, 64);
            int oi = __shfl_xor(bi, mm, 64);
            if (ov > bv || (ov == bv && oi < bi)) { bv = ov; bi = oi; }
        }
        if (part == 0)
            buckets[(((size_t)(b * H_ + h)) << 12) + tile * 64 + tok] = bi;
    }
}

// ---------------------------------------------------------------- stable counting sort
__global__ __launch_bounds__(256) void sort_kernel(const int* __restrict__ buckets,
                                                   int* __restrict__ st,
                                                   int* __restrict__ inv,
                                                   const float* __restrict__ rnrm,
                                                   float* __restrict__ rnrm_s) {
    __shared__ unsigned short hist[256][64];
    __shared__ int base[64];
    __shared__ int totals[64];
    int tid = threadIdx.x;
    const int* bkrow = buckets + (size_t)blockIdx.x * S_;
    const float* rnb = rnrm + (size_t)(blockIdx.x >> 3) * S_;

    unsigned int* h32 = (unsigned int*)hist;
    #pragma unroll
    for (int u = 0; u < 32; ++u) h32[u * 256 + tid] = 0;
    __syncthreads();

    #pragma unroll
    for (int u = 0; u < 16; ++u) {
        int t = tid * 16 + u;
        int bk = bkrow[t];
        hist[tid][bk]++;
    }
    __syncthreads();

    if (tid < 64) {
        int bucket = tid;
        int run = 0;
        for (int ch = 0; ch < 256; ++ch) {
            int v = hist[ch][bucket];
            hist[ch][bucket] = (unsigned short)run;
            run += v;
        }
        totals[bucket] = run;
    }
    __syncthreads();
    if (tid == 0) {
        int acc = 0;
        for (int k = 0; k < 64; ++k) { base[k] = acc; acc += totals[k]; }
    }
    __syncthreads();

    int* strow = st + (size_t)blockIdx.x * S_;
    int* invrow = inv + (size_t)blockIdx.x * S_;
    float* rnsrow = rnrm_s + (size_t)blockIdx.x * S_;
    #pragma unroll
    for (int u = 0; u < 16; ++u) {
        int t = tid * 16 + u;
        int bk = bkrow[t];
        int off = hist[tid][bk];
        hist[tid][bk] = (unsigned short)(off + 1);
        int pos = base[bk] + off;
        strow[pos] = t;
        invrow[t] = pos;
        rnsrow[pos] = rnb[t] * SCALE_;
    }
}

// ---------------------------------------------------------------- in-reg 4x4 transpose
__device__ __forceinline__ void transpose4(const float4 v, int g, float (&w_)[4]) {
    bool b0 = (g & 1) != 0, b1 = (g & 2) != 0;
    float k0 = b1 ? v.z : v.x;
    float k1 = b1 ? v.w : v.y;
    float s0 = b1 ? v.x : v.z;
    float s1 = b1 ? v.y : v.w;
    float r0 = __shfl_xor(s0, 32, 64);
    float r1 = __shfl_xor(s1, 32, 64);
    float kq_ = b0 ? k1 : k0;
    float rq_ = b0 ? r1 : r0;
    float sk  = b0 ? k0 : k1;
    float sr  = b0 ? r0 : r1;
    float tk_ = __shfl_xor(sk, 16, 64);
    float tr_ = __shfl_xor(sr, 16, 64);
    float A0 = b0 ? tk_ : kq_;
    float A1 = b0 ? kq_ : tk_;
    float B0 = b0 ? tr_ : rq_;
    float B1 = b0 ? rq_ : tr_;
    w_[0] = b1 ? B0 : A0;
    w_[1] = b1 ? B1 : A1;
    w_[2] = b1 ? A0 : B0;
    w_[3] = b1 ? A1 : B1;
}

// ---------------------------------------------------------------- strip MFMA attention
// One block per (b, strip of L_ consecutive chunks). Each chunk staged ONCE;
// previous chunk's K/V double-buffer serves as the look-back operand.
// 3 barriers/chunk; next-chunk K gather issued under PV.
template<bool DENSE>
__global__ __launch_bounds__(256, 2) void attn_strip_kernel(
        const float* __restrict__ qk, const float* __restrict__ rnrm_s,
        const float* __restrict__ vglob, const int* __restrict__ st,
        float* __restrict__ outnum, float* __restrict__ den,
        _Float16* __restrict__ snum, float* __restrict__ sden) {
    __shared__ int   toks[2][64];
    __shared__ float rnss[2][64];
    __shared__ short kbuf[2][8192];   // f16 K, swizzled (16 KB each)
    __shared__ short vbuf[2][8192];   // f16 V^T, swizzled (16 KB each)

    // XCD swizzle: 1024 blocks -> each XCD gets 128 contiguous logical blocks.
    const int p = blockIdx.x;
    const int lg = (p & 7) * 128 + (p >> 3);
    const int b = lg >> 6;
    const int strip = lg & 63;
    const int c0 = strip * L_;
    const int tid = threadIdx.x;
    const int w = tid >> 6, l = tid & 63, g = l >> 4, m = l & 15;
    const size_t bS = ((size_t)b << 12);
    const int* stb = st + ((size_t)b << 15);

    auto rns_base = [&](int c) -> size_t {
        return (((size_t)(b * H_ + (c >> 6))) << 12) + (size_t)(c & 63) * 64;
    };

    float4 kreg[8];
    float4 va[4], vb[4];

    auto issue_k = [&](const int* __restrict__ tk) {
        #pragma unroll
        for (int u = 0; u < 8; ++u) {
            int token = u * 8 + (tid >> 5);
            int cc = tid & 31;
            kreg[u] = *(const float4*)(qk + (bS + tk[token]) * D_ + cc * 4);
        }
    };
    auto write_k = [&](short* __restrict__ kb) {
        #pragma unroll
        for (int u = 0; u < 8; ++u) {
            int token = u * 8 + (tid >> 5);
            int cc = tid & 31;
            float4 vv = kreg[u];
            unsigned h0 = pack2f16(vv.x, vv.y), h1 = pack2f16(vv.z, vv.w);
            int kw = token * 128 + ((((cc >> 1) ^ (token & 7)) << 3) | ((cc & 1) << 2));
            *(int2*)&kb[kw] = make_int2((int)h0, (int)h1);
        }
    };
    auto issue_v = [&](const int* __restrict__ tk) {
        #pragma unroll
        for (int up = 0; up < 4; ++up) {
            int kq8 = w * 16 + (up & 1) * 8;
            int cc = (up >> 1) * 16 + m;
            va[up] = *(const float4*)(vglob + (bS + tk[kq8 + g]) * D_ + cc * 4);
            vb[up] = *(const float4*)(vglob + (bS + tk[kq8 + 4 + g]) * D_ + cc * 4);
        }
    };
    auto write_v = [&](short* __restrict__ vq) {
        #pragma unroll
        for (int up = 0; up < 4; ++up) {
            int kq8 = w * 16 + (up & 1) * 8;
            int cc = (up >> 1) * 16 + m;
            float wa[4], wb[4];
            transpose4(va[up], g, wa);
            transpose4(vb[up], g, wb);
            unsigned h0 = pack2f16(wa[0], wa[1]), h1 = pack2f16(wa[2], wa[3]);
            unsigned h2 = pack2f16(wb[0], wb[1]), h3 = pack2f16(wb[2], wb[3]);
            int d = cc * 4 + g;
            int ds = d ^ ((d >> 3) & 7);
            int kg = kq8 >> 3;
            int idx = (kg * 128 + ds) * 8;
            *(int4*)&vq[idx] = make_int4((int)h0, (int)h1, (int)h2, (int)h3);
        }
    };

    // ---- prologue: lists for c0-1 (slot 1) and c0 (slot 0); stage prev K/V
    const int cprev = (c0 + 511) & 511;
    if (tid < 64) {
        toks[1][tid] = stb[cprev * 64 + tid];
        rnss[1][tid] = rnrm_s[rns_base(cprev) + tid];
        toks[0][tid] = stb[c0 * 64 + tid];
        rnss[0][tid] = rnrm_s[rns_base(c0) + tid];
    }
    __syncthreads();
    issue_k(toks[1]);
    issue_v(toks[1]);
    write_k(kbuf[1]);
    write_v(vbuf[1]);
    __syncthreads();
    issue_k(toks[0]);                   // gather K of first chunk

    #pragma unroll 1
    for (int j = 0; j < L_; ++j) {
        const int c = c0 + j;
        const int cur = j & 1, prv = cur ^ 1;
        short* kbc = kbuf[cur];
        short* kbp = kbuf[prv];
        short* vbc = vbuf[cur];
        short* vbp = vbuf[prv];

        // ---- write K_c (gathered last iteration / prologue)
        write_k(kbc);
        __syncthreads();                // B1: kbc visible

        // ---- Q frags from kbc; issue V_c; QK self + prev
        f16x8 qh[4];
        #pragma unroll
        for (int s4 = 0; s4 < 4; ++s4) {
            int qr = (w * 16 + m) * 128 + (((s4 * 4 + g) ^ (m & 7)) << 3);
            qh[s4] = *(const f16x8*)&kbc[qr];
        }
        const int qtok_m = toks[cur][w * 16 + m];
        issue_v(toks[cur]);

        f32x4 e4s[4], e4p[4];
        float densum = 0.f;
        auto qk_one = [&](const short* __restrict__ kb,
                          const float* __restrict__ rns,
                          const int* __restrict__ tkp, int mode,
                          f32x4 (&e4)[4]) {
            #pragma unroll
            for (int kt = 0; kt < 4; ++kt) {
                f32x4 acc = (f32x4){0.f, 0.f, 0.f, 0.f};
                #pragma unroll
                for (int s4 = 0; s4 < 4; ++s4) {
                    int kr = (kt * 16 + m) * 128 + (((s4 * 4 + g) ^ (m & 7)) << 3);
                    f16x8 ah = *(const f16x8*)&kb[kr];
                    acc = __builtin_amdgcn_mfma_f32_16x16x32_f16(ah, qh[s4], acc, 0, 0, 0);
                }
                f32x4 rn4 = *(const f32x4*)&rns[kt * 16 + g * 4];
                int4v kt4;
                if (mode == 1) kt4 = *(const int4v*)&tkp[kt * 16 + g * 4];
                f32x4 e;
                #pragma unroll
                for (int r = 0; r < 4; ++r) {
                    float ev = __expf(acc[r] * rn4[r]);
                    if (mode == 0) {
                        if (kt == w && (g * 4 + r) == m) ev = 0.0f;
                    } else {
                        if (kt4[r] == qtok_m) ev = 0.0f;
                    }
                    e[r] = ev;
                    densum += ev;
                }
                e4[kt] = e;
            }
        };
        qk_one(kbc, rnss[cur], toks[cur], 0, e4s);
        qk_one(kbp, rnss[prv], toks[prv], 1, e4p);
        __syncthreads();                // B2: QK reads + prev-list reads done

        // prefetch next chunk's list into the slot just freed (prv)
        if (j + 1 < L_ && tid < 64) {
            int cn = c + 1;
            toks[prv][tid] = stb[cn * 64 + tid];
            rnss[prv][tid] = rnrm_s[rns_base(cn) + tid];
        }
        write_v(vbc);
        __syncthreads();                // B3: vbc + prefetch visible

        if (j + 1 < L_) issue_k(toks[prv]);   // next K gather under PV

        // ---- PV self + prev
        f32x4 acc_o[8];
        #pragma unroll
        for (int dt = 0; dt < 8; ++dt) acc_o[dt] = (f32x4){0.f, 0.f, 0.f, 0.f};
        auto pv_one = [&](const short* __restrict__ vq, const f32x4 (&e4)[4]) {
            #pragma unroll
            for (int s = 0; s < 2; ++s) {
                float pav[8];
                #pragma unroll
                for (int c2 = 0; c2 < 2; ++c2) {
                    int srcLane = ((g & 1) * 2 + c2) * 16 + m;
                    #pragma unroll
                    for (int r = 0; r < 4; ++r) {
                        float v0 = __shfl(e4[2 * s][r], srcLane, 64);
                        float v1 = __shfl(e4[2 * s + 1][r], srcLane, 64);
                        pav[c2 * 4 + r] = (g >> 1) ? v1 : v0;
                    }
                }
                F16x8U pahu;
                #pragma unroll
                for (int j2 = 0; j2 < 4; ++j2)
                    pahu.i[j2] = (int)pack2f16(pav[2 * j2], pav[2 * j2 + 1]);
                f16x8 pah = pahu.h;
                #pragma unroll
                for (int dt = 0; dt < 8; ++dt) {
                    int d = dt * 16 + m;
                    int ds = d ^ ((d >> 3) & 7);
                    int base = ((s * 4 + g) * 128 + ds) * 8;
                    f16x8 vh = *(const f16x8*)&vq[base];
                    acc_o[dt] = __builtin_amdgcn_mfma_f32_16x16x32_f16(pah, vh, acc_o[dt], 0, 0, 0);
                }
            }
        };
        pv_one(vbc, e4s);
        pv_one(vbp, e4p);

        // ---- epilogue for chunk c
        densum += __shfl_xor(densum, 16, 64);
        densum += __shfl_xor(densum, 32, 64);

        if (DENSE) {
            const int h = c >> 6;
            const size_t base = (((size_t)(b * H_ + h)) << 12) + (size_t)(c & 63) * 64;
            #pragma unroll
            for (int r = 0; r < 4; ++r) {
                int row = w * 16 + g * 4 + r;
                _Float16* nrow = snum + (base + row) * D_;
                #pragma unroll
                for (int dt = 0; dt < 8; ++dt)
                    __builtin_nontemporal_store((_Float16)acc_o[dt][r], nrow + dt * 16 + m);
            }
            if (g == 0) __builtin_nontemporal_store(densum, sden + base + w * 16 + m);
        } else {
            if (g == 0) atomicAdd(den + bS + qtok_m, densum);
            int4v q4tok = *(const int4v*)&toks[cur][w * 16 + g * 4];
            #pragma unroll
            for (int r = 0; r < 4; ++r) {
                float* obase = outnum + ((bS + q4tok[r]) * D_);
                #pragma unroll
                for (int dt = 0; dt < 8; ++dt)
                    atomicAdd(obase + dt * 16 + m, acc_o[dt][r]);
            }
        }
    }
}

// ---------------------------------------------------------------- combine
__global__ __launch_bounds__(256) void combine_kernel(
        const _Float16* __restrict__ snum, const float* __restrict__ sden,
        const int* __restrict__ inv, float* __restrict__ out) {
    int wv = threadIdx.x >> 6, l = threadIdx.x & 63;
    int t = blockIdx.x * 4 + wv;          // 0 .. B*S-1
    int b = t >> 12, s = t & 4095;
    float s0 = 0.f, s1 = 0.f, dsum = 0.f;
    #pragma unroll
    for (int h = 0; h < H_; ++h) {
        int bh = b * H_ + h;
        int pos = inv[((size_t)bh << 12) + s];
        size_t row = ((size_t)bh << 12) + pos;
        dsum += __builtin_nontemporal_load(sden + row);
        unsigned uv = __builtin_nontemporal_load(
            (const unsigned*)(snum + row * D_ + 2 * l));
        unsigned short us0 = (unsigned short)(uv & 0xFFFFu);
        unsigned short us1 = (unsigned short)(uv >> 16);
        _Float16 h0, h1;
        __builtin_memcpy(&h0, &us0, 2);
        __builtin_memcpy(&h1, &us1, 2);
        s0 += (float)h0;
        s1 += (float)h1;
    }
    float rd = 1.0f / dsum;
    f32x2v o2 = {s0 * rd, s1 * rd};
    __builtin_nontemporal_store(o2, (f32x2v*)(out + (size_t)t * D_ + 2 * l));
}

// ---------------------------------------------------------------- divide (fallback)
__global__ __launch_bounds__(256) void div_kernel(float* __restrict__ out,
                                                  const float* __restrict__ den) {
    int i = blockIdx.x * 256 + threadIdx.x;
    float4 o = ((float4*)out)[i];
    float dn = den[i >> 5];
    ((float4*)out)[i] = make_float4(o.x / dn, o.y / dn, o.z / dn, o.w / dn);
}

// ---------------------------------------------------------------- launch
extern "C" void kernel_launch(void* const* d_in, const int* in_sizes, int n_in,
                              void* d_out, int out_size, void* d_ws, size_t ws_size,
                              hipStream_t stream) {
    const float* qk  = (const float*)d_in[0];
    const float* v   = (const float*)d_in[1];
    const float* rot = (const float*)d_in[2];
    float* out = (float*)d_out;

    char* ws = (char*)d_ws;
    float* rnrm    = (float*)ws;                        //   262,144 B
    int* buckets   = (int*)(ws + 262144);               // 2,097,152 B
    int* inv       = buckets;                           // aliased (RAW per index)
    int* st        = (int*)(ws + 2359296);              // 2,097,152 B
    float* rnrm_s  = (float*)(ws + 4456448);            // 2,097,152 B
    float* sden    = (float*)(ws + 6553600);            // 2,097,152 B
    short* rth     = (short*)(ws + 8650752);            //    65,536 B
    short* rtl     = (short*)(ws + 8716288);            //    65,536 B
    _Float16* snum = (_Float16*)(ws + 8781824);         // 134,217,728 B
    const size_t need = 8781824ull + 134217728ull;

    norm_kernel<<<B_ * S_ / 8, 256, 0, stream>>>(qk, rnrm);
    prep_rot_kernel<<<32, 256, 0, stream>>>(rot, rth, rtl);
    hash_kernel<<<B_ * (S_ / 64) * 4, 256, 0, stream>>>(qk, rot, rth, rtl, buckets);
    sort_kernel<<<B_ * H_, 256, 0, stream>>>(buckets, st, inv, rnrm, rnrm_s);

    if (ws_size >= need) {
        attn_strip_kernel<true><<<B_ * C_ / L_, 256, 0, stream>>>(
            qk, rnrm_s, v, st, nullptr, nullptr, snum, sden);
        combine_kernel<<<B_ * S_ / 4, 256, 0, stream>>>(snum, sden, inv, out);
    } else {
        float* den = sden;
        hipMemsetAsync(out, 0, (size_t)B_ * S_ * D_ * 4, stream);
        hipMemsetAsync(den, 0, (size_t)B_ * S_ * 4, stream);
        attn_strip_kernel<false><<<B_ * C_ / L_, 256, 0, stream>>>(
            qk, rnrm_s, v, st, out, den, nullptr, nullptr);
        div_kernel<<<B_ * S_ * D_ / 4 / 256, 256, 0, stream>>>(out, den);
    }
}

// Round 20
// 222.224 us; speedup vs baseline: 1.5432x; 1.0044x over previous
//
#include <hip/hip_runtime.h>
#include <hip/hip_bf16.h>

// LSH attention (Reformer-style), B=16, S=4096, D=128, H=8, bucket=64.
// norm -> prep_rot -> zero-LDS MFMA hash (hp-split, 4-term bf16, u64 argmax,
// rare f64 fallback) -> counting sort -> strip MFMA attention (8 chunks/block,
// K/V staged once, double-buffered, triple-buffered lists -> 2 barriers/chunk,
// f16 MFMA, dense nt-stores) -> combine.

#define B_ 16
#define S_ 4096
#define D_ 128
#define H_ 8
#define C_ 512          // H * n_buckets
#define L_ 8            // chunks per strip
#define SCALE_ 0.08838834764831845f   // D^-0.5

typedef __attribute__((ext_vector_type(8))) short bf16x8;
typedef __attribute__((ext_vector_type(8))) _Float16 f16x8;
typedef __attribute__((ext_vector_type(2))) _Float16 f16x2t;
typedef __attribute__((ext_vector_type(4))) float f32x4;
typedef __attribute__((ext_vector_type(2))) float f32x2v;
typedef __attribute__((ext_vector_type(4))) int int4v;

union BF8U { int4v i; bf16x8 b; };
union F16x8U { int4v i; f16x8 h; };

__device__ __forceinline__ unsigned hi_pack(float x0, float x1) {
    unsigned a, b;
    __builtin_memcpy(&b, &x0, 4);
    __builtin_memcpy(&a, &x1, 4);
    return __builtin_amdgcn_perm(a, b, 0x07060302u);   // [x0.b2,x0.b3,x1.b2,x1.b3]
}
__device__ __forceinline__ float truncbf(float x) {
    unsigned u; __builtin_memcpy(&u, &x, 4);
    u &= 0xFFFF0000u;
    float f; __builtin_memcpy(&f, &u, 4);
    return f;
}
__device__ __forceinline__ unsigned pack2f16(float x0, float x1) {
    f16x2t h = {(_Float16)x0, (_Float16)x1};
    unsigned u; __builtin_memcpy(&u, &h, 4);
    return u;
}
__device__ __forceinline__ unsigned enc_ks(unsigned u) {
    return (u & 0x80000000u) ? ~u : (u | 0x80000000u);
}
__device__ __forceinline__ float dec_ks(unsigned ks) {
    unsigned u = (ks & 0x80000000u) ? (ks ^ 0x80000000u) : ~ks;
    float f; __builtin_memcpy(&f, &u, 4);
    return f;
}

// ---------------------------------------------------------------- row 1/norm
__global__ __launch_bounds__(256) void norm_kernel(const float* __restrict__ qk,
                                                   float* __restrict__ rnrm) {
    int half = threadIdx.x >> 5;
    int lane32 = threadIdx.x & 31;
    size_t row = (size_t)blockIdx.x * 8 + half;
    float4 vv = ((const float4*)(qk + row * D_))[lane32];
    float ss = vv.x * vv.x + vv.y * vv.y + vv.z * vv.z + vv.w * vv.w;
    #pragma unroll
    for (int m = 1; m < 32; m <<= 1) ss += __shfl_xor(ss, m, 64);
    if (lane32 == 0) rnrm[row] = 1.0f / fmaxf(sqrtf(ss), 1e-12f);
}

// ---------------------------------------------------------------- prep rot
__global__ __launch_bounds__(256) void prep_rot_kernel(const float* __restrict__ rot,
                                                       short* __restrict__ rth,
                                                       short* __restrict__ rtl) {
    int x = blockIdx.x * 256 + threadIdx.x;   // 0..8191
    int hp = x >> 11;
    int ia = (x >> 5) & 63;
    int ft = x & 31;
    float v0 = rot[(size_t)(ft * 4 + 0) * 256 + hp * 64 + ia];
    float v1 = rot[(size_t)(ft * 4 + 1) * 256 + hp * 64 + ia];
    float v2 = rot[(size_t)(ft * 4 + 2) * 256 + hp * 64 + ia];
    float v3 = rot[(size_t)(ft * 4 + 3) * 256 + hp * 64 + ia];
    unsigned h0 = hi_pack(v0, v1), h1 = hi_pack(v2, v3);
    unsigned l0 = hi_pack(v0 - truncbf(v0), v1 - truncbf(v1));
    unsigned l1 = hi_pack(v2 - truncbf(v2), v3 - truncbf(v3));
    int off = ia * 128 + ((((ft >> 1) ^ (ia & 7)) << 3) | ((ft & 1) << 2));
    *(int2*)&rth[hp * 8192 + off] = make_int2((int)h0, (int)h1);
    *(int2*)&rtl[hp * 8192 + off] = make_int2((int)l0, (int)l1);
}

// ---------------------------------------------------------------- MFMA hashing
// One block per (b, tile, hp). 4-term bf16 split (exact to f32 rounding).
__global__ __launch_bounds__(256, 4) void hash_kernel(
        const float* __restrict__ qk, const float* __restrict__ rot,
        const short* __restrict__ rth, const short* __restrict__ rtl,
        int* __restrict__ buckets) {
    __shared__ unsigned char flags[2][64];

    const int bid = blockIdx.x;
    const int b = bid >> 8;
    const int tile = (bid >> 2) & 63;
    const int hp = bid & 3;
    const int tid = threadIdx.x;
    const int w = tid >> 6, l = tid & 63, g = l >> 4, m = l & 15;

    if (tid < 8) ((int4*)flags)[tid] = make_int4(0, 0, 0, 0);
    __syncthreads();

    const float* qrow = qk + ((size_t)b * S_ + (size_t)tile * 64 + w * 16 + m) * D_;
    bf16x8 qh[4], qlr[4];
    #pragma unroll
    for (int s = 0; s < 4; ++s) {
        float4 xa = *(const float4*)(qrow + s * 32 + g * 8);
        float4 xb = *(const float4*)(qrow + s * 32 + g * 8 + 4);
        BF8U hu, lu;
        hu.i[0] = (int)hi_pack(xa.x, xa.y); hu.i[1] = (int)hi_pack(xa.z, xa.w);
        hu.i[2] = (int)hi_pack(xb.x, xb.y); hu.i[3] = (int)hi_pack(xb.z, xb.w);
        lu.i[0] = (int)hi_pack(xa.x - truncbf(xa.x), xa.y - truncbf(xa.y));
        lu.i[1] = (int)hi_pack(xa.z - truncbf(xa.z), xa.w - truncbf(xa.w));
        lu.i[2] = (int)hi_pack(xb.x - truncbf(xb.x), xb.y - truncbf(xb.y));
        lu.i[3] = (int)hi_pack(xb.z - truncbf(xb.z), xb.w - truncbf(xb.w));
        qh[s] = hu.b; qlr[s] = lu.b;
    }

    f32x4 dots_n[4];
    #pragma unroll
    for (int nt = 0; nt < 4; ++nt) {
        f32x4 acc = (f32x4){0.f, 0.f, 0.f, 0.f};
        #pragma unroll
        for (int s = 0; s < 4; ++s) {
            int kr = hp * 8192 + (nt * 16 + m) * 128 + (((s * 4 + g) ^ (m & 7)) << 3);
            bf16x8 bh = *(const bf16x8*)&rth[kr];
            bf16x8 bl = *(const bf16x8*)&rtl[kr];
            acc = __builtin_amdgcn_mfma_f32_16x16x32_bf16(qh[s], bh, acc, 0, 0, 0);
            acc = __builtin_amdgcn_mfma_f32_16x16x32_bf16(qh[s], bl, acc, 0, 0, 0);
            acc = __builtin_amdgcn_mfma_f32_16x16x32_bf16(qlr[s], bh, acc, 0, 0, 0);
            acc = __builtin_amdgcn_mfma_f32_16x16x32_bf16(qlr[s], bl, acc, 0, 0, 0);
        }
        dots_n[nt] = acc;
    }

    #pragma unroll
    for (int hh = 0; hh < 2; ++hh) {
        int h = hp * 2 + hh;
        #pragma unroll
        for (int r = 0; r < 4; ++r) {
            unsigned long long kM = 0ull, kS = 0ull;
            #pragma unroll
            for (int nn = 0; nn < 2; ++nn) {
                float v = dots_n[hh * 2 + nn][r];
                unsigned u; __builtin_memcpy(&u, &v, 4);
                int i = nn * 16 + m;
                unsigned long long kp =
                    ((unsigned long long)enc_ks(u) << 6) | (unsigned)(63 - i);
                unsigned long long kn =
                    ((unsigned long long)enc_ks(u ^ 0x80000000u) << 6) |
                    (unsigned)(63 - (i + 32));
                if (kp > kM) { kS = kM; kM = kp; } else if (kp > kS) kS = kp;
                if (kn > kM) { kS = kM; kM = kn; } else if (kn > kS) kS = kn;
            }
            #pragma unroll
            for (int st = 1; st <= 8; st <<= 1) {
                unsigned long long oM = __shfl_xor(kM, st, 64);
                unsigned long long oS = __shfl_xor(kS, st, 64);
                unsigned long long lo = kM < oM ? kM : oM;
                kM = kM > oM ? kM : oM;
                unsigned long long hs = kS > oS ? kS : oS;
                kS = hs > lo ? hs : lo;
            }
            if (m == 0) {
                int tok = w * 16 + g * 4 + r;
                int i1 = 63 - (int)(kM & 63ull);
                float v1 = dec_ks((unsigned)(kM >> 6));
                float v2 = dec_ks((unsigned)(kS >> 6));
                if (v1 - v2 < 1e-3f) flags[hh][tok] = 1;
                buckets[(((size_t)(b * H_ + h)) << 12) + tile * 64 + tok] = i1;
            }
        }
    }
    __syncthreads();

    int tok = tid >> 2, part = tid & 3;
    const float* qtok = qk + ((size_t)b * S_ + (size_t)tile * 64 + tok) * D_;
    for (int hh = 0; hh < 2; ++hh) {
        if (!flags[hh][tok]) continue;
        int h = hp * 2 + hh;
        double pd[8] = {0, 0, 0, 0, 0, 0, 0, 0};
        #pragma unroll 2
        for (int f = 0; f < 128; ++f) {
            double q = (double)qtok[f];
            const float* rp = rot + (size_t)f * 256 + h * 32 + part * 8;
            float4 r0 = *(const float4*)rp;
            float4 r1 = *(const float4*)(rp + 4);
            pd[0] = fma(q, (double)r0.x, pd[0]);
            pd[1] = fma(q, (double)r0.y, pd[1]);
            pd[2] = fma(q, (double)r0.z, pd[2]);
            pd[3] = fma(q, (double)r0.w, pd[3]);
            pd[4] = fma(q, (double)r1.x, pd[4]);
            pd[5] = fma(q, (double)r1.y, pd[5]);
            pd[6] = fma(q, (double)r1.z, pd[6]);
            pd[7] = fma(q, (double)r1.w, pd[7]);
        }
        double bv = -1e300; int bi = 0;
        #pragma unroll
        for (int ii = 0; ii < 8; ++ii) {
            int i = part * 8 + ii;
            double v = pd[ii];
            if (v > bv || (v == bv && i < bi)) { bv = v; bi = i; }
            double nv = -v; int ni = i + 32;
            if (nv > bv || (nv == bv && ni < bi)) { bv = nv; bi = ni; }
        }
        #pragma unroll
        for (int mm = 1; mm <= 2; mm <<= 1) {
            double ov = __shfl_xor(bv, mm, 64);
            int oi = __shfl_xor(bi, mm, 64);
            if (ov > bv || (ov == bv && oi < bi)) { bv = ov; bi = oi; }
        }
        if (part == 0)
            buckets[(((size_t)(b * H_ + h)) << 12) + tile * 64 + tok] = bi;
    }
}

// ---------------------------------------------------------------- stable counting sort
__global__ __launch_bounds__(256) void sort_kernel(const int* __restrict__ buckets,
                                                   int* __restrict__ st,
                                                   int* __restrict__ inv,
                                                   const float* __restrict__ rnrm,
                                                   float* __restrict__ rnrm_s) {
    __shared__ unsigned short hist[256][64];
    __shared__ int base[64];
    __shared__ int totals[64];
    int tid = threadIdx.x;
    const int* bkrow = buckets + (size_t)blockIdx.x * S_;
    const float* rnb = rnrm + (size_t)(blockIdx.x >> 3) * S_;

    unsigned int* h32 = (unsigned int*)hist;
    #pragma unroll
    for (int u = 0; u < 32; ++u) h32[u * 256 + tid] = 0;
    __syncthreads();

    #pragma unroll
    for (int u = 0; u < 16; ++u) {
        int t = tid * 16 + u;
        int bk = bkrow[t];
        hist[tid][bk]++;
    }
    __syncthreads();

    if (tid < 64) {
        int bucket = tid;
        int run = 0;
        for (int ch = 0; ch < 256; ++ch) {
            int v = hist[ch][bucket];
            hist[ch][bucket] = (unsigned short)run;
            run += v;
        }
        totals[bucket] = run;
    }
    __syncthreads();
    if (tid == 0) {
        int acc = 0;
        for (int k = 0; k < 64; ++k) { base[k] = acc; acc += totals[k]; }
    }
    __syncthreads();

    int* strow = st + (size_t)blockIdx.x * S_;
    int* invrow = inv + (size_t)blockIdx.x * S_;
    float* rnsrow = rnrm_s + (size_t)blockIdx.x * S_;
    #pragma unroll
    for (int u = 0; u < 16; ++u) {
        int t = tid * 16 + u;
        int bk = bkrow[t];
        int off = hist[tid][bk];
        hist[tid][bk] = (unsigned short)(off + 1);
        int pos = base[bk] + off;
        strow[pos] = t;
        invrow[t] = pos;
        rnsrow[pos] = rnb[t] * SCALE_;
    }
}

// ---------------------------------------------------------------- in-reg 4x4 transpose
__device__ __forceinline__ void transpose4(const float4 v, int g, float (&w_)[4]) {
    bool b0 = (g & 1) != 0, b1 = (g & 2) != 0;
    float k0 = b1 ? v.z : v.x;
    float k1 = b1 ? v.w : v.y;
    float s0 = b1 ? v.x : v.z;
    float s1 = b1 ? v.y : v.w;
    float r0 = __shfl_xor(s0, 32, 64);
    float r1 = __shfl_xor(s1, 32, 64);
    float kq_ = b0 ? k1 : k0;
    float rq_ = b0 ? r1 : r0;
    float sk  = b0 ? k0 : k1;
    float sr  = b0 ? r0 : r1;
    float tk_ = __shfl_xor(sk, 16, 64);
    float tr_ = __shfl_xor(sr, 16, 64);
    float A0 = b0 ? tk_ : kq_;
    float A1 = b0 ? kq_ : tk_;
    float B0 = b0 ? tr_ : rq_;
    float B1 = b0 ? rq_ : tr_;
    w_[0] = b1 ? B0 : A0;
    w_[1] = b1 ? B1 : A1;
    w_[2] = b1 ? A0 : B0;
    w_[3] = b1 ? A1 : B1;
}

// ---------------------------------------------------------------- strip MFMA attention
// One block per (b, strip of L_ consecutive chunks). Each chunk staged ONCE;
// previous chunk's K/V double-buffer serves as the look-back operand.
// Token/rnrm lists TRIPLE-buffered -> list prefetch needs no dedicated barrier
// -> 2 barriers/chunk. Dataflow order identical to the verified 3-barrier
// version: write_k; B1; [prefetch ns | issue_v | QK | write_v]; B2;
// [issue_k ns | PV | store].
template<bool DENSE>
__global__ __launch_bounds__(256, 2) void attn_strip_kernel(
        const float* __restrict__ qk, const float* __restrict__ rnrm_s,
        const float* __restrict__ vglob, const int* __restrict__ st,
        float* __restrict__ outnum, float* __restrict__ den,
        _Float16* __restrict__ snum, float* __restrict__ sden) {
    __shared__ int   toks[3][64];
    __shared__ float rnss[3][64];
    __shared__ short kbuf[2][8192];   // f16 K, swizzled (16 KB each)
    __shared__ short vbuf[2][8192];   // f16 V^T, swizzled (16 KB each)

    // XCD swizzle: 1024 blocks -> each XCD gets 128 contiguous logical blocks.
    const int p = blockIdx.x;
    const int lg = (p & 7) * 128 + (p >> 3);
    const int b = lg >> 6;
    const int strip = lg & 63;
    const int c0 = strip * L_;
    const int tid = threadIdx.x;
    const int w = tid >> 6, l = tid & 63, g = l >> 4, m = l & 15;
    const size_t bS = ((size_t)b << 12);
    const int* stb = st + ((size_t)b << 15);

    auto rns_base = [&](int c) -> size_t {
        return (((size_t)(b * H_ + (c >> 6))) << 12) + (size_t)(c & 63) * 64;
    };

    float4 kreg[8];
    float4 va[4], vb[4];

    auto issue_k = [&](const int* __restrict__ tk) {
        #pragma unroll
        for (int u = 0; u < 8; ++u) {
            int token = u * 8 + (tid >> 5);
            int cc = tid & 31;
            kreg[u] = *(const float4*)(qk + (bS + tk[token]) * D_ + cc * 4);
        }
    };
    auto write_k = [&](short* __restrict__ kb) {
        #pragma unroll
        for (int u = 0; u < 8; ++u) {
            int token = u * 8 + (tid >> 5);
            int cc = tid & 31;
            float4 vv = kreg[u];
            unsigned h0 = pack2f16(vv.x, vv.y), h1 = pack2f16(vv.z, vv.w);
            int kw = token * 128 + ((((cc >> 1) ^ (token & 7)) << 3) | ((cc & 1) << 2));
            *(int2*)&kb[kw] = make_int2((int)h0, (int)h1);
        }
    };
    auto issue_v = [&](const int* __restrict__ tk) {
        #pragma unroll
        for (int up = 0; up < 4; ++up) {
            int kq8 = w * 16 + (up & 1) * 8;
            int cc = (up >> 1) * 16 + m;
            va[up] = *(const float4*)(vglob + (bS + tk[kq8 + g]) * D_ + cc * 4);
            vb[up] = *(const float4*)(vglob + (bS + tk[kq8 + 4 + g]) * D_ + cc * 4);
        }
    };
    auto write_v = [&](short* __restrict__ vq) {
        #pragma unroll
        for (int up = 0; up < 4; ++up) {
            int kq8 = w * 16 + (up & 1) * 8;
            int cc = (up >> 1) * 16 + m;
            float wa[4], wb[4];
            transpose4(va[up], g, wa);
            transpose4(vb[up], g, wb);
            unsigned h0 = pack2f16(wa[0], wa[1]), h1 = pack2f16(wa[2], wa[3]);
            unsigned h2 = pack2f16(wb[0], wb[1]), h3 = pack2f16(wb[2], wb[3]);
            int d = cc * 4 + g;
            int ds = d ^ ((d >> 3) & 7);
            int kg = kq8 >> 3;
            int idx = (kg * 128 + ds) * 8;
            *(int4*)&vq[idx] = make_int4((int)h0, (int)h1, (int)h2, (int)h3);
        }
    };

    // ---- prologue: lists for c0-1 (slot 2) and c0 (slot 0); stage prev K/V
    const int cprev = (c0 + 511) & 511;
    if (tid < 64) {
        toks[2][tid] = stb[cprev * 64 + tid];
        rnss[2][tid] = rnrm_s[rns_base(cprev) + tid];
        toks[0][tid] = stb[c0 * 64 + tid];
        rnss[0][tid] = rnrm_s[rns_base(c0) + tid];
    }
    __syncthreads();
    issue_k(toks[2]);
    issue_v(toks[2]);
    write_k(kbuf[1]);
    write_v(vbuf[1]);
    __syncthreads();
    issue_k(toks[0]);                   // gather K of first chunk

    #pragma unroll 1
    for (int j = 0; j < L_; ++j) {
        const int c = c0 + j;
        const int cur = j & 1, prv = cur ^ 1;
        const int cs = j % 3;           // current list slot
        const int ps = (j + 2) % 3;     // previous list slot
        const int ns = (j + 1) % 3;     // next list slot (free: last read at j-1)
        short* kbc = kbuf[cur];
        short* kbp = kbuf[prv];
        short* vbc = vbuf[cur];
        short* vbp = vbuf[prv];

        // ---- write K_c (gathered last iteration / prologue)
        write_k(kbc);
        __syncthreads();                // B1: kbc visible; slot ns reads all done

        // prefetch next chunk's list into slot ns (no reader until after B2)
        if (j + 1 < L_ && tid < 64) {
            int cn = c + 1;
            toks[ns][tid] = stb[cn * 64 + tid];
            rnss[ns][tid] = rnrm_s[rns_base(cn) + tid];
        }

        // ---- Q frags from kbc; issue V_c; QK self + prev
        f16x8 qh[4];
        #pragma unroll
        for (int s4 = 0; s4 < 4; ++s4) {
            int qr = (w * 16 + m) * 128 + (((s4 * 4 + g) ^ (m & 7)) << 3);
            qh[s4] = *(const f16x8*)&kbc[qr];
        }
        const int qtok_m = toks[cs][w * 16 + m];
        issue_v(toks[cs]);

        f32x4 e4s[4], e4p[4];
        float densum = 0.f;
        auto qk_one = [&](const short* __restrict__ kb,
                          const float* __restrict__ rns,
                          const int* __restrict__ tkp, int mode,
                          f32x4 (&e4)[4]) {
            #pragma unroll
            for (int kt = 0; kt < 4; ++kt) {
                f32x4 acc = (f32x4){0.f, 0.f, 0.f, 0.f};
                #pragma unroll
                for (int s4 = 0; s4 < 4; ++s4) {
                    int kr = (kt * 16 + m) * 128 + (((s4 * 4 + g) ^ (m & 7)) << 3);
                    f16x8 ah = *(const f16x8*)&kb[kr];
                    acc = __builtin_amdgcn_mfma_f32_16x16x32_f16(ah, qh[s4], acc, 0, 0, 0);
                }
                f32x4 rn4 = *(const f32x4*)&rns[kt * 16 + g * 4];
                int4v kt4;
                if (mode == 1) kt4 = *(const int4v*)&tkp[kt * 16 + g * 4];
                f32x4 e;
                #pragma unroll
                for (int r = 0; r < 4; ++r) {
                    float ev = __expf(acc[r] * rn4[r]);
                    if (mode == 0) {
                        if (kt == w && (g * 4 + r) == m) ev = 0.0f;
                    } else {
                        if (kt4[r] == qtok_m) ev = 0.0f;
                    }
                    e[r] = ev;
                    densum += ev;
                }
                e4[kt] = e;
            }
        };
        qk_one(kbc, rnss[cs], toks[cs], 0, e4s);
        qk_one(kbp, rnss[ps], toks[ps], 1, e4p);

        write_v(vbc);                   // V_c (vbc last read at j-1's PV, pre-B1)
        __syncthreads();                // B2: vbc + list prefetch visible

        if (j + 1 < L_) issue_k(toks[ns]);   // next K gather under PV

        // ---- PV self + prev
        f32x4 acc_o[8];
        #pragma unroll
        for (int dt = 0; dt < 8; ++dt) acc_o[dt] = (f32x4){0.f, 0.f, 0.f, 0.f};
        auto pv_one = [&](const short* __restrict__ vq, const f32x4 (&e4)[4]) {
            #pragma unroll
            for (int s = 0; s < 2; ++s) {
                float pav[8];
                #pragma unroll
                for (int c2 = 0; c2 < 2; ++c2) {
                    int srcLane = ((g & 1) * 2 + c2) * 16 + m;
                    #pragma unroll
                    for (int r = 0; r < 4; ++r) {
                        float v0 = __shfl(e4[2 * s][r], srcLane, 64);
                        float v1 = __shfl(e4[2 * s + 1][r], srcLane, 64);
                        pav[c2 * 4 + r] = (g >> 1) ? v1 : v0;
                    }
                }
                F16x8U pahu;
                #pragma unroll
                for (int j2 = 0; j2 < 4; ++j2)
                    pahu.i[j2] = (int)pack2f16(pav[2 * j2], pav[2 * j2 + 1]);
                f16x8 pah = pahu.h;
                #pragma unroll
                for (int dt = 0; dt < 8; ++dt) {
                    int d = dt * 16 + m;
                    int ds = d ^ ((d >> 3) & 7);
                    int base = ((s * 4 + g) * 128 + ds) * 8;
                    f16x8 vh = *(const f16x8*)&vq[base];
                    acc_o[dt] = __builtin_amdgcn_mfma_f32_16x16x32_f16(pah, vh, acc_o[dt], 0, 0, 0);
                }
            }
        };
        pv_one(vbc, e4s);
        pv_one(vbp, e4p);

        // ---- epilogue for chunk c
        densum += __shfl_xor(densum, 16, 64);
        densum += __shfl_xor(densum, 32, 64);

        if (DENSE) {
            const int h = c >> 6;
            const size_t base = (((size_t)(b * H_ + h)) << 12) + (size_t)(c & 63) * 64;
            #pragma unroll
            for (int r = 0; r < 4; ++r) {
                int row = w * 16 + g * 4 + r;
                _Float16* nrow = snum + (base + row) * D_;
                #pragma unroll
                for (int dt = 0; dt < 8; ++dt)
                    __builtin_nontemporal_store((_Float16)acc_o[dt][r], nrow + dt * 16 + m);
            }
            if (g == 0) __builtin_nontemporal_store(densum, sden + base + w * 16 + m);
        } else {
            if (g == 0) atomicAdd(den + bS + qtok_m, densum);
            int4v q4tok = *(const int4v*)&toks[cs][w * 16 + g * 4];
            #pragma unroll
            for (int r = 0; r < 4; ++r) {
                float* obase = outnum + ((bS + q4tok[r]) * D_);
                #pragma unroll
                for (int dt = 0; dt < 8; ++dt)
                    atomicAdd(obase + dt * 16 + m, acc_o[dt][r]);
            }
        }
    }
}

// ---------------------------------------------------------------- combine
__global__ __launch_bounds__(256) void combine_kernel(
        const _Float16* __restrict__ snum, const float* __restrict__ sden,
        const int* __restrict__ inv, float* __restrict__ out) {
    int wv = threadIdx.x >> 6, l = threadIdx.x & 63;
    int t = blockIdx.x * 4 + wv;          // 0 .. B*S-1
    int b = t >> 12, s = t & 4095;
    float s0 = 0.f, s1 = 0.f, dsum = 0.f;
    #pragma unroll
    for (int h = 0; h < H_; ++h) {
        int bh = b * H_ + h;
        int pos = inv[((size_t)bh << 12) + s];
        size_t row = ((size_t)bh << 12) + pos;
        dsum += __builtin_nontemporal_load(sden + row);
        unsigned uv = __builtin_nontemporal_load(
            (const unsigned*)(snum + row * D_ + 2 * l));
        unsigned short us0 = (unsigned short)(uv & 0xFFFFu);
        unsigned short us1 = (unsigned short)(uv >> 16);
        _Float16 h0, h1;
        __builtin_memcpy(&h0, &us0, 2);
        __builtin_memcpy(&h1, &us1, 2);
        s0 += (float)h0;
        s1 += (float)h1;
    }
    float rd = 1.0f / dsum;
    f32x2v o2 = {s0 * rd, s1 * rd};
    __builtin_nontemporal_store(o2, (f32x2v*)(out + (size_t)t * D_ + 2 * l));
}

// ---------------------------------------------------------------- divide (fallback)
__global__ __launch_bounds__(256) void div_kernel(float* __restrict__ out,
                                                  const float* __restrict__ den) {
    int i = blockIdx.x * 256 + threadIdx.x;
    float4 o = ((float4*)out)[i];
    float dn = den[i >> 5];
    ((float4*)out)[i] = make_float4(o.x / dn, o.y / dn, o.z / dn, o.w / dn);
}

// ---------------------------------------------------------------- launch
extern "C" void kernel_launch(void* const* d_in, const int* in_sizes, int n_in,
                              void* d_out, int out_size, void* d_ws, size_t ws_size,
                              hipStream_t stream) {
    const float* qk  = (const float*)d_in[0];
    const float* v   = (const float*)d_in[1];
    const float* rot = (const float*)d_in[2];
    float* out = (float*)d_out;

    char* ws = (char*)d_ws;
    float* rnrm    = (float*)ws;                        //   262,144 B
    int* buckets   = (int*)(ws + 262144);               // 2,097,152 B
    int* inv       = buckets;                           // aliased (RAW per index)
    int* st        = (int*)(ws + 2359296);              // 2,097,152 B
    float* rnrm_s  = (float*)(ws + 4456448);            // 2,097,152 B
    float* sden    = (float*)(ws + 6553600);            // 2,097,152 B
    short* rth     = (short*)(ws + 8650752);            //    65,536 B
    short* rtl     = (short*)(ws + 8716288);            //    65,536 B
    _Float16* snum = (_Float16*)(ws + 8781824);         // 134,217,728 B
    const size_t need = 8781824ull + 134217728ull;

    norm_kernel<<<B_ * S_ / 8, 256, 0, stream>>>(qk, rnrm);
    prep_rot_kernel<<<32, 256, 0, stream>>>(rot, rth, rtl);
    hash_kernel<<<B_ * (S_ / 64) * 4, 256, 0, stream>>>(qk, rot, rth, rtl, buckets);
    sort_kernel<<<B_ * H_, 256, 0, stream>>>(buckets, st, inv, rnrm, rnrm_s);

    if (ws_size >= need) {
        attn_strip_kernel<true><<<B_ * C_ / L_, 256, 0, stream>>>(
            qk, rnrm_s, v, st, nullptr, nullptr, snum, sden);
        combine_kernel<<<B_ * S_ / 4, 256, 0, stream>>>(snum, sden, inv, out);
    } else {
        float* den = sden;
        hipMemsetAsync(out, 0, (size_t)B_ * S_ * D_ * 4, stream);
        hipMemsetAsync(den, 0, (size_t)B_ * S_ * 4, stream);
        attn_strip_kernel<false><<<B_ * C_ / L_, 256, 0, stream>>>(
            qk, rnrm_s, v, st, out, den, nullptr, nullptr);
        div_kernel<<<B_ * S_ * D_ / 4 / 256, 256, 0, stream>>>(out, den);
    }
}